// Round 4
// baseline (2513.093 us; speedup 1.0000x reference)
//
#include <hip/hip_runtime.h>
#include <math.h>

#define NN 50000
#define NE 800000
#define NGRAPH 100
#define NPG 500
#define NB_SCAN 196
#define CHAIN_ELEMS ((size_t)NN * 64)
#define CH4 ((size_t)NN * 16)          // float4 elements per plane
#define QF 16                          // floats per quarter row
#define QPLANE ((size_t)NN * QF)       // floats per quarter plane
#define NGRP 12500                     // node groups (4 nodes each)
#define GRID_Q 12504                   // 8 | GRID_Q; 3126 blocks per quarter

typedef long long ll;
typedef float f32x4_t __attribute__((ext_vector_type(4)));

__device__ __forceinline__ void unpack(ll v, int& r, float& w) {
    r = (int)(v & 0xffffffffLL);
    w = __int_as_float((int)(v >> 32));
}

__device__ __forceinline__ float4 f4fma(float w, float4 v, float4 a) {
    a.x += w * v.x; a.y += w * v.y; a.z += w * v.z; a.w += w * v.w;
    return a;
}

// ---------------- setup kernels ----------------

__global__ void k_deg(const int* __restrict__ col, int* __restrict__ degi) {
    int e = blockIdx.x * blockDim.x + threadIdx.x;
    if (e < NE) atomicAdd(&degi[col[e]], 1);
}

__global__ void k_dh(const int* __restrict__ degi, float* __restrict__ dh) {
    int i = blockIdx.x * blockDim.x + threadIdx.x;
    if (i < NN) {
        int d = degi[i];
        dh[i] = d > 0 ? (float)(1.0 / sqrt((double)d)) : 0.0f;
    }
}

__global__ void k_bsum(const int* __restrict__ cnt, int* __restrict__ bsum) {
    __shared__ int sh[256];
    int i = blockIdx.x * 256 + threadIdx.x;
    sh[threadIdx.x] = (i < NN) ? cnt[i] : 0;
    __syncthreads();
    for (int s = 128; s > 0; s >>= 1) {
        if (threadIdx.x < s) sh[threadIdx.x] += sh[threadIdx.x + s];
        __syncthreads();
    }
    if (threadIdx.x == 0) bsum[blockIdx.x] = sh[0];
}

__global__ void k_bscan(const int* __restrict__ bsum, int* __restrict__ boff) {
    __shared__ int sh[2][256];
    int v = (threadIdx.x < NB_SCAN) ? bsum[threadIdx.x] : 0;
    int cur = 0;
    sh[0][threadIdx.x] = v;
    __syncthreads();
    for (int s = 1; s < 256; s <<= 1) {
        int val = sh[cur][threadIdx.x];
        if ((int)threadIdx.x >= s) val += sh[cur][threadIdx.x - s];
        sh[cur ^ 1][threadIdx.x] = val;
        cur ^= 1;
        __syncthreads();
    }
    if (threadIdx.x < NB_SCAN) boff[threadIdx.x] = sh[cur][threadIdx.x] - v;
}

__global__ void k_scan2(const int* __restrict__ cnt, const int* __restrict__ boff,
                        int* __restrict__ off) {
    __shared__ int sh[2][256];
    int i = blockIdx.x * 256 + threadIdx.x;
    int v = (i < NN) ? cnt[i] : 0;
    int cur = 0;
    sh[0][threadIdx.x] = v;
    __syncthreads();
    for (int s = 1; s < 256; s <<= 1) {
        int val = sh[cur][threadIdx.x];
        if ((int)threadIdx.x >= s) val += sh[cur][threadIdx.x - s];
        sh[cur ^ 1][threadIdx.x] = val;
        cur ^= 1;
        __syncthreads();
    }
    if (i < NN) off[i] = boff[blockIdx.x] + sh[cur][threadIdx.x] - v;
}

__global__ void k_fill(const int* __restrict__ row, const int* __restrict__ col,
                       const float* __restrict__ dh, const int* __restrict__ off,
                       int* __restrict__ cursor, ll* __restrict__ csrp) {
    int e = blockIdx.x * blockDim.x + threadIdx.x;
    if (e >= NE) return;
    int r = row[e], c = col[e];
    int pos = off[c] + atomicAdd(&cursor[c], 1);
    float w = dh[r] * dh[c];
    csrp[pos] = ((ll)__float_as_int(w) << 32) | (unsigned int)r;
}

// transpose x[NN][64] -> xq[4][NN][16] (quarter-major), one float4 per thread
__global__ void k_xpose(const float* __restrict__ x, float* __restrict__ xq) {
    size_t o = (size_t)blockIdx.x * 256 + threadIdx.x;   // float4 index < CH4
    size_t q = o / ((size_t)NN * 4);
    size_t rem = o - q * ((size_t)NN * 4);
    size_t n = rem >> 2;
    size_t j = rem & 3;
    float4 v = *(const float4*)&x[n * 64 + q * QF + j * 4];
    ((float4*)xq)[o] = v;
}

// ---------------- recurrence kernel ----------------
// Quarter-major [4][NN][16] planes; quarter-per-XCD-pair sharding (R2-proven:
// FETCH 297 -> ~44 MB) + R0's one-shot loop shape (overhead once per wave,
// plain cached loads -- R2's NT csrp put a ~900-cycle HBM miss at the head of
// every dependency chain; that was the latency bug).
// block b: xcd = b&7, q = xcd>>1. Per quarter: 3126 blocks x 4 waves cover
// the 12500 node groups one-shot. wave = 4 nodes x one quarter.
// lane = ns*16 + eg*4 + cq. Sharding is a cache-locality heuristic only;
// coverage/correctness are mapping-independent. FP order per output element
// is identical to the R0 kernel (same edge partition, same reduce tree).

template <bool INIT>
__global__ __launch_bounds__(256) void k_prop(
    const float* __restrict__ Tcur, const float* __restrict__ Tprev,
    float* __restrict__ Tnext, const int* __restrict__ off,
    const int* __restrict__ degi, const ll* __restrict__ csrp) {
    int b = blockIdx.x;
    int xcd = b & 7;
    int q = xcd >> 1;
    int lb = ((b >> 3) << 1) | (b & 1);          // block index within quarter
    int g = lb * 4 + (threadIdx.x >> 6);         // node group
    if (g >= NGRP) return;                       // wave-uniform exit
    int lane = threadIdx.x & 63;
    int ns = lane >> 4;
    int eg = (lane >> 2) & 3;
    int cq = lane & 3;
    int node = g * 4 + ns;
    int s = off[node], e = s + degi[node];
    const float* tb = Tcur + (size_t)q * QPLANE + cq * 4;
    float4 a0 = make_float4(0.f, 0.f, 0.f, 0.f);
    float4 a1 = make_float4(0.f, 0.f, 0.f, 0.f);
    int i = s;
    for (; i + 8 <= e; i += 8) {
        int r0, r1; float w0, w1;
        unpack(csrp[i + eg], r0, w0);
        unpack(csrp[i + 4 + eg], r1, w1);
        float4 v0 = *(const float4*)(tb + (size_t)r0 * QF);
        float4 v1 = *(const float4*)(tb + (size_t)r1 * QF);
        a0 = f4fma(w0, v0, a0);
        a1 = f4fma(w1, v1, a1);
    }
    for (; i < e; i += 4) {
        int idx = i + eg;
        bool act = idx < e;
        int r; float w;
        unpack(csrp[act ? idx : (e - 1)], r, w);
        if (!act) w = 0.f;
        float4 v = *(const float4*)(tb + (size_t)r * QF);
        a0 = f4fma(w, v, a0);
    }
    float4 a = make_float4(a0.x + a1.x, a0.y + a1.y, a0.z + a1.z, a0.w + a1.w);
    a.x += __shfl_xor(a.x, 4); a.y += __shfl_xor(a.y, 4);
    a.z += __shfl_xor(a.z, 4); a.w += __shfl_xor(a.w, 4);
    a.x += __shfl_xor(a.x, 8); a.y += __shfl_xor(a.y, 8);
    a.z += __shfl_xor(a.z, 8); a.w += __shfl_xor(a.w, 8);
    if ((lane & 12) == 0) {                      // eg == 0: 4 writer lanes/node
        size_t o = (size_t)q * QPLANE + (size_t)node * QF + cq * 4;
        float4 t;
        if (INIT) {
            t = make_float4(-a.x, -a.y, -a.z, -a.w);
        } else {
            float4 pv = *(const float4*)&Tprev[o];
            t = make_float4(-2.f * a.x - pv.x, -2.f * a.y - pv.y,
                            -2.f * a.z - pv.z, -2.f * a.w - pv.w);
        }
        *(float4*)&Tnext[o] = t;
    }
}

// ---------------- combine: acc planes from NS pool slots (float4) -----------
// Planes are quarter-major, combine is elementwise on flat arrays: unchanged.

struct CombCfg {
    float c0[4];
    float ck[4][8];
    int   plane[4];
};

template <int NS, int NT>
__global__ __launch_bounds__(256) void k_combine(
    const float4* __restrict__ src0, const float4* __restrict__ pool,
    float4* __restrict__ accb, CombCfg cfg, int first, int doabs) {
    size_t v = (size_t)blockIdx.x * 256 + threadIdx.x;   // < NN*16
    float4 tv[NS];
#pragma unroll
    for (int m = 0; m < NS; ++m) tv[m] = pool[(size_t)m * CH4 + v];
    float4 s0 = first ? src0[v] : make_float4(0.f, 0.f, 0.f, 0.f);
#pragma unroll
    for (int t = 0; t < NT; ++t) {
        size_t o = (size_t)cfg.plane[t] * CH4 + v;
        float4 a;
        if (first) {
            float c = cfg.c0[t];
            a = make_float4(c * s0.x, c * s0.y, c * s0.z, c * s0.w);
        } else {
            a = accb[o];
        }
#pragma unroll
        for (int m = 0; m < NS; ++m) a = f4fma(cfg.ck[t][m], tv[m], a);
        if (doabs) a = make_float4(fabsf(a.x), fabsf(a.y), fabsf(a.z), fabsf(a.w));
        accb[o] = a;
    }
}

// ---------------- moments (quarter-major addressing) ----------------
__global__ void k_moments(const float* __restrict__ xq, const float* __restrict__ hacc,
                          const float* __restrict__ acc2, float* __restrict__ out) {
    int g = blockIdx.y;
    int col = blockIdx.x * 256 + threadIdx.x;
    if (col >= 704) return;
    const float* src;
    int c0;
    if (col < 64)       { src = xq;   c0 = col; }
    else if (col < 320) { int p = (col - 64) >> 6;  src = hacc + (size_t)p * CHAIN_ELEMS; c0 = (col - 64) & 63; }
    else                { int p = (col - 320) >> 6; src = acc2 + (size_t)p * CHAIN_ELEMS; c0 = (col - 320) & 63; }
    const float* sp = src + (size_t)(c0 >> 4) * QPLANE + (c0 & 15);
    double s1 = 0, s2 = 0, s3 = 0, s4 = 0;
    int base = g * NPG;
    for (int i = 0; i < NPG; ++i) {
        double v = (double)sp[(size_t)(base + i) * QF];
        double v2 = v * v;
        s1 += v; s2 += v2; s3 += v2 * v; s4 += v2 * v2;
    }
    double n = (double)NPG;
    double mu = s1 / n;
    double E2 = s2 / n, E3 = s3 / n, E4 = s4 / n;
    double m2 = E2 - mu * mu;
    double m3 = E3 - 3.0 * mu * E2 + 2.0 * mu * mu * mu;
    double m4 = E4 - 4.0 * mu * E3 + 6.0 * mu * mu * E2 - 3.0 * mu * mu * mu * mu;
    float m2f = (float)m2;
    float skew = 0.f, kurt = -3.f;
    if (m2f > 0.f) {
        skew = (float)(m3 / (m2 * sqrt(m2)));
        if (skew > 1e15f) skew = 0.f;
        kurt = (float)(m4 / (m2 * m2) - 3.0);
        if (kurt > 1e15f) kurt = -3.f;
    }
    size_t ob = (size_t)g * 2816 + col;
    out[ob]        = (float)mu;
    out[ob + 704]  = m2f;
    out[ob + 1408] = skew;
    out[ob + 2112] = kurt;
}

// ---------------- host ----------------

extern "C" void kernel_launch(void* const* d_in, const int* in_sizes, int n_in,
                              void* d_out, int out_size, void* d_ws, size_t ws_size,
                              hipStream_t stream) {
    const float* x = (const float*)d_in[0];
    const int* ei  = (const int*)d_in[1];
    const int* row = ei;
    const int* col = ei + NE;
    float* out = (float*)d_out;

    // Chebyshev coefficients [17][4], double precision (matches numpy)
    float C[17][4];
    {
        const int Nc = 17;
        const int scales[4] = {2, 4, 8, 16};
        for (int si = 0; si < 4; ++si) {
            double ker[17];
            for (int j = 0; j < Nc; ++j) {
                double num = cos(M_PI * (j + 0.5) / Nc);
                double b = -num;
                double v = pow(b, (double)(scales[si] / 2)) - pow(b, (double)scales[si]);
                if (v < 0) v = 0;
                ker[j] = sqrt(v);
            }
            for (int o = 0; o < Nc; ++o) {
                double acc = 0;
                for (int j = 0; j < Nc; ++j) acc += ker[j] * cos(M_PI * o * (j + 0.5) / Nc);
                C[o][si] = (float)(2.0 / Nc * acc);
            }
        }
    }

    // workspace carve: plan A pool=8 (~250 MB), plan B pool=4 (~199 MB)
    int*   degi; float* dh; int* off; int* cursor; int* bsum; int* boff;
    ll*    csrp; float* pool; float* hacc; float* acc2; float* xq;
    int SLOTS = 8;
    for (int attempt = 0; attempt < 2; ++attempt) {
        char* p = (char*)d_ws;
        auto alloc = [&](size_t bytes) -> void* {
            void* r = (void*)p;
            p += (bytes + 255) & ~(size_t)255;
            return r;
        };
        degi   = (int*)alloc((size_t)NN * 4);
        dh     = (float*)alloc((size_t)NN * 4);
        off    = (int*)alloc((size_t)NN * 4);
        cursor = (int*)alloc((size_t)NN * 4);
        bsum   = (int*)alloc((size_t)NB_SCAN * 4);
        boff   = (int*)alloc((size_t)NB_SCAN * 4);
        csrp   = (ll*)alloc((size_t)NE * 8);
        xq     = (float*)alloc(CHAIN_ELEMS * 4);
        pool   = (float*)alloc((size_t)SLOTS * CHAIN_ELEMS * 4);
        hacc   = (float*)alloc((size_t)4 * CHAIN_ELEMS * 4);
        acc2   = (float*)alloc((size_t)6 * CHAIN_ELEMS * 4);
        if ((size_t)(p - (char*)d_ws) <= ws_size) break;
        SLOTS = 4;
    }
    const int CAD = SLOTS;   // combine cadence

    hipMemsetAsync(degi, 0, (size_t)NN * 4, stream);
    hipMemsetAsync(cursor, 0, (size_t)NN * 4, stream);

    k_deg  <<<(NE + 255) / 256, 256, 0, stream>>>(col, degi);
    k_dh   <<<(NN + 255) / 256, 256, 0, stream>>>(degi, dh);
    k_bsum <<<NB_SCAN, 256, 0, stream>>>(degi, bsum);
    k_bscan<<<1, 256, 0, stream>>>(bsum, boff);
    k_scan2<<<NB_SCAN, 256, 0, stream>>>(degi, boff, off);
    k_fill <<<(NE + 255) / 256, 256, 0, stream>>>(row, col, dh, off, cursor, csrp);

    const int GRID_C = (int)(CH4 / 256);   // 3125
    k_xpose<<<GRID_C, 256, 0, stream>>>(x, xq);

    auto slot = [&](int k) { return pool + (size_t)((k - 1) & (CAD - 1)) * CHAIN_ELEMS; };

    auto launch_combine = [&](int nt, const float* src, float* accb,
                              CombCfg& cfg, int first, int doabs) {
        const float4* s4 = (const float4*)src;
        const float4* p4 = (const float4*)pool;
        float4* a4 = (float4*)accb;
        if (CAD == 8) {
            if (nt == 4) k_combine<8, 4><<<GRID_C, 256, 0, stream>>>(s4, p4, a4, cfg, first, doabs);
            if (nt == 3) k_combine<8, 3><<<GRID_C, 256, 0, stream>>>(s4, p4, a4, cfg, first, doabs);
            if (nt == 2) k_combine<8, 2><<<GRID_C, 256, 0, stream>>>(s4, p4, a4, cfg, first, doabs);
            if (nt == 1) k_combine<8, 1><<<GRID_C, 256, 0, stream>>>(s4, p4, a4, cfg, first, doabs);
        } else {
            if (nt == 4) k_combine<4, 4><<<GRID_C, 256, 0, stream>>>(s4, p4, a4, cfg, first, doabs);
            if (nt == 3) k_combine<4, 3><<<GRID_C, 256, 0, stream>>>(s4, p4, a4, cfg, first, doabs);
            if (nt == 2) k_combine<4, 2><<<GRID_C, 256, 0, stream>>>(s4, p4, a4, cfg, first, doabs);
            if (nt == 1) k_combine<4, 1><<<GRID_C, 256, 0, stream>>>(s4, p4, a4, cfg, first, doabs);
        }
    };

    // run one chain: src (quarter-major [4][NN][16]) -> acc planes of accb
    auto run_chain = [&](const float* src, float* accb,
                         const int* scl, const int* pln, int nt) {
        k_prop<true><<<GRID_Q, 256, 0, stream>>>(src, nullptr, slot(1),
                                                 off, degi, csrp);
        for (int k = 2; k <= 16; ++k) {
            const float* Tprev = (k == 2) ? src : slot(k - 2);
            k_prop<false><<<GRID_Q, 256, 0, stream>>>(slot(k - 1), Tprev, slot(k),
                                                      off, degi, csrp);
            if ((k % CAD) == 0) {
                CombCfg cfg;
                for (int t = 0; t < nt; ++t) {
                    int si = scl[t];
                    cfg.c0[t] = 0.5f * C[0][si];
                    cfg.plane[t] = pln[t];
                    for (int m = 0; m < CAD; ++m) cfg.ck[t][m] = C[k - CAD + 1 + m][si];
                }
                launch_combine(nt, src, accb, cfg, (k == CAD) ? 1 : 0,
                               (k == 16) ? 1 : 0);
            }
        }
    };

    // ---- phase 1: xq -> hacc planes 0..3 (|h| per scale) ----
    {
        const int scl[4] = {0, 1, 2, 3};
        const int pln[4] = {0, 1, 2, 3};
        run_chain(xq, hacc, scl, pln, 4);
    }

    // ---- phase 2: 3 chains on hacc planes 0..2 ----
    {
        const int scl0[3] = {1, 2, 3}; const int pln0[3] = {0, 1, 3};
        run_chain(hacc + 0 * CHAIN_ELEMS, acc2, scl0, pln0, 3);
        const int scl1[2] = {2, 3};    const int pln1[2] = {2, 4};
        run_chain(hacc + 1 * CHAIN_ELEMS, acc2, scl1, pln1, 2);
        const int scl2[1] = {3};       const int pln2[1] = {5};
        run_chain(hacc + 2 * CHAIN_ELEMS, acc2, scl2, pln2, 1);
    }

    // ---- moments ----
    dim3 mg(3, NGRAPH);
    k_moments<<<mg, 256, 0, stream>>>(xq, hacc, acc2, out);
}

// Round 5
// 1986.342 us; speedup vs baseline: 1.2652x; 1.2652x over previous
//
#include <hip/hip_runtime.h>
#include <math.h>

#define NN 50000
#define NE 800000
#define NGRAPH 100
#define NPG 500
#define NB_SCAN 196
#define CHAIN_ELEMS ((size_t)NN * 64)
#define CH4 ((size_t)NN * 16)          // float4 (or half4) elements per plane
#define GRID_PROP (NN / 4)             // 4 nodes (waves) per 256-thr block

typedef long long ll;
typedef _Float16 h4_t __attribute__((ext_vector_type(4)));

__device__ __forceinline__ void unpack(ll v, int& r, float& w) {
    r = (int)(v & 0xffffffffLL);
    w = __int_as_float((int)(v >> 32));
}

__device__ __forceinline__ float4 f4fma(float w, float4 v, float4 a) {
    a.x += w * v.x; a.y += w * v.y; a.z += w * v.z; a.w += w * v.w;
    return a;
}

__device__ __forceinline__ float4 h4f4(h4_t h) {
    return make_float4((float)h.x, (float)h.y, (float)h.z, (float)h.w);
}

__device__ __forceinline__ h4_t f4h4(float4 v) {
    h4_t h;
    h.x = (_Float16)v.x; h.y = (_Float16)v.y;
    h.z = (_Float16)v.z; h.w = (_Float16)v.w;
    return h;
}

// ---------------- setup kernels ----------------

__global__ void k_deg(const int* __restrict__ col, int* __restrict__ degi) {
    int e = blockIdx.x * blockDim.x + threadIdx.x;
    if (e < NE) atomicAdd(&degi[col[e]], 1);
}

__global__ void k_dh(const int* __restrict__ degi, float* __restrict__ dh) {
    int i = blockIdx.x * blockDim.x + threadIdx.x;
    if (i < NN) {
        int d = degi[i];
        dh[i] = d > 0 ? (float)(1.0 / sqrt((double)d)) : 0.0f;
    }
}

__global__ void k_bsum(const int* __restrict__ cnt, int* __restrict__ bsum) {
    __shared__ int sh[256];
    int i = blockIdx.x * 256 + threadIdx.x;
    sh[threadIdx.x] = (i < NN) ? cnt[i] : 0;
    __syncthreads();
    for (int s = 128; s > 0; s >>= 1) {
        if (threadIdx.x < s) sh[threadIdx.x] += sh[threadIdx.x + s];
        __syncthreads();
    }
    if (threadIdx.x == 0) bsum[blockIdx.x] = sh[0];
}

__global__ void k_bscan(const int* __restrict__ bsum, int* __restrict__ boff) {
    __shared__ int sh[2][256];
    int v = (threadIdx.x < NB_SCAN) ? bsum[threadIdx.x] : 0;
    int cur = 0;
    sh[0][threadIdx.x] = v;
    __syncthreads();
    for (int s = 1; s < 256; s <<= 1) {
        int val = sh[cur][threadIdx.x];
        if ((int)threadIdx.x >= s) val += sh[cur][threadIdx.x - s];
        sh[cur ^ 1][threadIdx.x] = val;
        cur ^= 1;
        __syncthreads();
    }
    if (threadIdx.x < NB_SCAN) boff[threadIdx.x] = sh[cur][threadIdx.x] - v;
}

__global__ void k_scan2(const int* __restrict__ cnt, const int* __restrict__ boff,
                        int* __restrict__ off) {
    __shared__ int sh[2][256];
    int i = blockIdx.x * 256 + threadIdx.x;
    int v = (i < NN) ? cnt[i] : 0;
    int cur = 0;
    sh[0][threadIdx.x] = v;
    __syncthreads();
    for (int s = 1; s < 256; s <<= 1) {
        int val = sh[cur][threadIdx.x];
        if ((int)threadIdx.x >= s) val += sh[cur][threadIdx.x - s];
        sh[cur ^ 1][threadIdx.x] = val;
        cur ^= 1;
        __syncthreads();
    }
    if (i < NN) off[i] = boff[blockIdx.x] + sh[cur][threadIdx.x] - v;
}

__global__ void k_fill(const int* __restrict__ row, const int* __restrict__ col,
                       const float* __restrict__ dh, const int* __restrict__ off,
                       int* __restrict__ cursor, ll* __restrict__ csrp) {
    int e = blockIdx.x * blockDim.x + threadIdx.x;
    if (e >= NE) return;
    int r = row[e], c = col[e];
    int pos = off[c] + atomicAdd(&cursor[c], 1);
    float w = dh[r] * dh[c];
    csrp[pos] = ((ll)__float_as_int(w) << 32) | (unsigned int)r;
}

// fp32 -> fp16 plane copy (phase-2 gather table init)
__global__ void k_tohalf(const float* __restrict__ src, _Float16* __restrict__ dst) {
    size_t i = ((size_t)blockIdx.x * 256 + threadIdx.x) * 4;
    float4 v = *(const float4*)&src[i];
    *(h4_t*)&dst[i] = f4h4(v);
}

// ---------------- phase-1 recurrence (R0-validated, fp32 [NN][64]) ----------
// wave = 1 node. lane = eg*16 + cq: eg = edge subgroup (0..3), cq = col quad.
// 256 B row gathers, 2 accumulators, plain cached loads.

template <bool INIT>
__global__ __launch_bounds__(256) void k_prop(
    const float* __restrict__ Tcur, const float* __restrict__ Tprev,
    float* __restrict__ Tnext, const int* __restrict__ off,
    const int* __restrict__ degi, const ll* __restrict__ csrp) {
    int node = blockIdx.x * 4 + (threadIdx.x >> 6);
    int lane = threadIdx.x & 63;
    int eg = lane >> 4;
    int cq = lane & 15;
    int s = off[node], e = s + degi[node];
    const float* tb = Tcur + (size_t)cq * 4;
    float4 a0 = make_float4(0.f, 0.f, 0.f, 0.f);
    float4 a1 = make_float4(0.f, 0.f, 0.f, 0.f);
    float4 pv = INIT ? make_float4(0.f, 0.f, 0.f, 0.f)
                     : *(const float4*)&Tprev[(size_t)node * 64 + cq * 4];
    int i = s;
    for (; i + 8 <= e; i += 8) {
        int r0, r1; float w0, w1;
        unpack(csrp[i + eg], r0, w0);
        unpack(csrp[i + 4 + eg], r1, w1);
        float4 v0 = *(const float4*)(tb + (size_t)r0 * 64);
        float4 v1 = *(const float4*)(tb + (size_t)r1 * 64);
        a0 = f4fma(w0, v0, a0);
        a1 = f4fma(w1, v1, a1);
    }
    for (; i < e; i += 4) {
        int idx = i + eg;
        bool act = idx < e;
        int r; float w;
        unpack(csrp[act ? idx : (e - 1)], r, w);
        if (!act) w = 0.f;
        float4 v = *(const float4*)(tb + (size_t)r * 64);
        a0 = f4fma(w, v, a0);
    }
    float4 g = make_float4(a0.x + a1.x, a0.y + a1.y, a0.z + a1.z, a0.w + a1.w);
    g.x += __shfl_xor(g.x, 16); g.y += __shfl_xor(g.y, 16);
    g.z += __shfl_xor(g.z, 16); g.w += __shfl_xor(g.w, 16);
    g.x += __shfl_xor(g.x, 32); g.y += __shfl_xor(g.y, 32);
    g.z += __shfl_xor(g.z, 32); g.w += __shfl_xor(g.w, 32);
    float4 t;
    if (INIT) {
        t = make_float4(-g.x, -g.y, -g.z, -g.w);
    } else {
        t = make_float4(-2.f * g.x - pv.x, -2.f * g.y - pv.y,
                        -2.f * g.z - pv.z, -2.f * g.w - pv.w);
    }
    if (eg == 0) *(float4*)&Tnext[(size_t)node * 64 + cq * 4] = t;
}

// ---------------- phase-2 recurrence, fp16 state [NN][64] halves ------------
// Same geometry as k_prop; rows are 128 B (half the request bytes on the
// ~6.7 TB/s divergent-request wall). Weights + accumulation + reduce fp32;
// only the stored T_k state is fp16.

template <bool INIT>
__global__ __launch_bounds__(256) void k_prop16(
    const _Float16* __restrict__ Tcur, const _Float16* __restrict__ Tprev,
    _Float16* __restrict__ Tnext, const int* __restrict__ off,
    const int* __restrict__ degi, const ll* __restrict__ csrp) {
    int node = blockIdx.x * 4 + (threadIdx.x >> 6);
    int lane = threadIdx.x & 63;
    int eg = lane >> 4;
    int cq = lane & 15;
    int s = off[node], e = s + degi[node];
    const _Float16* tb = Tcur + (size_t)cq * 4;
    float4 a0 = make_float4(0.f, 0.f, 0.f, 0.f);
    float4 a1 = make_float4(0.f, 0.f, 0.f, 0.f);
    float4 pv;
    if (INIT) {
        pv = make_float4(0.f, 0.f, 0.f, 0.f);
    } else {
        h4_t ph = *(const h4_t*)&Tprev[(size_t)node * 64 + cq * 4];
        pv = h4f4(ph);
    }
    int i = s;
    for (; i + 8 <= e; i += 8) {
        int r0, r1; float w0, w1;
        unpack(csrp[i + eg], r0, w0);
        unpack(csrp[i + 4 + eg], r1, w1);
        h4_t h0 = *(const h4_t*)(tb + (size_t)r0 * 64);
        h4_t h1 = *(const h4_t*)(tb + (size_t)r1 * 64);
        a0 = f4fma(w0, h4f4(h0), a0);
        a1 = f4fma(w1, h4f4(h1), a1);
    }
    for (; i < e; i += 4) {
        int idx = i + eg;
        bool act = idx < e;
        int r; float w;
        unpack(csrp[act ? idx : (e - 1)], r, w);
        if (!act) w = 0.f;
        h4_t h = *(const h4_t*)(tb + (size_t)r * 64);
        a0 = f4fma(w, h4f4(h), a0);
    }
    float4 g = make_float4(a0.x + a1.x, a0.y + a1.y, a0.z + a1.z, a0.w + a1.w);
    g.x += __shfl_xor(g.x, 16); g.y += __shfl_xor(g.y, 16);
    g.z += __shfl_xor(g.z, 16); g.w += __shfl_xor(g.w, 16);
    g.x += __shfl_xor(g.x, 32); g.y += __shfl_xor(g.y, 32);
    g.z += __shfl_xor(g.z, 32); g.w += __shfl_xor(g.w, 32);
    float4 t;
    if (INIT) {
        t = make_float4(-g.x, -g.y, -g.z, -g.w);
    } else {
        t = make_float4(-2.f * g.x - pv.x, -2.f * g.y - pv.y,
                        -2.f * g.z - pv.z, -2.f * g.w - pv.w);
    }
    if (eg == 0) *(h4_t*)&Tnext[(size_t)node * 64 + cq * 4] = f4h4(t);
}

// ---------------- combine: fp32 pool slots (phase 1) ------------------------

struct CombCfg {
    float c0[4];
    float ck[4][8];
    int   plane[4];
};

template <int NS, int NT>
__global__ __launch_bounds__(256) void k_combine(
    const float4* __restrict__ src0, const float4* __restrict__ pool,
    float4* __restrict__ accb, CombCfg cfg, int first, int doabs) {
    size_t v = (size_t)blockIdx.x * 256 + threadIdx.x;   // < NN*16
    float4 tv[NS];
#pragma unroll
    for (int m = 0; m < NS; ++m) tv[m] = pool[(size_t)m * CH4 + v];
    float4 s0 = first ? src0[v] : make_float4(0.f, 0.f, 0.f, 0.f);
#pragma unroll
    for (int t = 0; t < NT; ++t) {
        size_t o = (size_t)cfg.plane[t] * CH4 + v;
        float4 a;
        if (first) {
            float c = cfg.c0[t];
            a = make_float4(c * s0.x, c * s0.y, c * s0.z, c * s0.w);
        } else {
            a = accb[o];
        }
#pragma unroll
        for (int m = 0; m < NS; ++m) a = f4fma(cfg.ck[t][m], tv[m], a);
        if (doabs) a = make_float4(fabsf(a.x), fabsf(a.y), fabsf(a.z), fabsf(a.w));
        accb[o] = a;
    }
}

// ---------------- combine: fp16 pool slots (phase 2), fp32 acc --------------
// src0 (first-call T0 term) stays the exact fp32 hacc plane.

template <int NS, int NT>
__global__ __launch_bounds__(256) void k_combine16(
    const float4* __restrict__ src0, const h4_t* __restrict__ pool,
    float4* __restrict__ accb, CombCfg cfg, int first, int doabs) {
    size_t v = (size_t)blockIdx.x * 256 + threadIdx.x;   // < NN*16
    float4 tv[NS];
#pragma unroll
    for (int m = 0; m < NS; ++m) tv[m] = h4f4(pool[(size_t)m * CH4 + v]);
    float4 s0 = first ? src0[v] : make_float4(0.f, 0.f, 0.f, 0.f);
#pragma unroll
    for (int t = 0; t < NT; ++t) {
        size_t o = (size_t)cfg.plane[t] * CH4 + v;
        float4 a;
        if (first) {
            float c = cfg.c0[t];
            a = make_float4(c * s0.x, c * s0.y, c * s0.z, c * s0.w);
        } else {
            a = accb[o];
        }
#pragma unroll
        for (int m = 0; m < NS; ++m) a = f4fma(cfg.ck[t][m], tv[m], a);
        if (doabs) a = make_float4(fabsf(a.x), fabsf(a.y), fabsf(a.z), fabsf(a.w));
        accb[o] = a;
    }
}

// ---------------- moments (row-major) ----------------
__global__ void k_moments(const float* __restrict__ x, const float* __restrict__ hacc,
                          const float* __restrict__ acc2, float* __restrict__ out) {
    int g = blockIdx.y;
    int col = blockIdx.x * 256 + threadIdx.x;
    if (col >= 704) return;
    const float* src;
    int c0;
    if (col < 64)       { src = x;    c0 = col; }
    else if (col < 320) { int p = (col - 64) >> 6;  src = hacc + (size_t)p * CHAIN_ELEMS; c0 = (col - 64) & 63; }
    else                { int p = (col - 320) >> 6; src = acc2 + (size_t)p * CHAIN_ELEMS; c0 = (col - 320) & 63; }
    double s1 = 0, s2 = 0, s3 = 0, s4 = 0;
    int base = g * NPG;
    for (int i = 0; i < NPG; ++i) {
        double v = (double)src[(size_t)(base + i) * 64 + c0];
        double v2 = v * v;
        s1 += v; s2 += v2; s3 += v2 * v; s4 += v2 * v2;
    }
    double n = (double)NPG;
    double mu = s1 / n;
    double E2 = s2 / n, E3 = s3 / n, E4 = s4 / n;
    double m2 = E2 - mu * mu;
    double m3 = E3 - 3.0 * mu * E2 + 2.0 * mu * mu * mu;
    double m4 = E4 - 4.0 * mu * E3 + 6.0 * mu * mu * E2 - 3.0 * mu * mu * mu * mu;
    float m2f = (float)m2;
    float skew = 0.f, kurt = -3.f;
    if (m2f > 0.f) {
        skew = (float)(m3 / (m2 * sqrt(m2)));
        if (skew > 1e15f) skew = 0.f;
        kurt = (float)(m4 / (m2 * m2) - 3.0);
        if (kurt > 1e15f) kurt = -3.f;
    }
    size_t ob = (size_t)g * 2816 + col;
    out[ob]        = (float)mu;
    out[ob + 704]  = m2f;
    out[ob + 1408] = skew;
    out[ob + 2112] = kurt;
}

// ---------------- host ----------------

extern "C" void kernel_launch(void* const* d_in, const int* in_sizes, int n_in,
                              void* d_out, int out_size, void* d_ws, size_t ws_size,
                              hipStream_t stream) {
    const float* x = (const float*)d_in[0];
    const int* ei  = (const int*)d_in[1];
    const int* row = ei;
    const int* col = ei + NE;
    float* out = (float*)d_out;

    // Chebyshev coefficients [17][4], double precision (matches numpy)
    float C[17][4];
    {
        const int Nc = 17;
        const int scales[4] = {2, 4, 8, 16};
        for (int si = 0; si < 4; ++si) {
            double ker[17];
            for (int j = 0; j < Nc; ++j) {
                double num = cos(M_PI * (j + 0.5) / Nc);
                double b = -num;
                double v = pow(b, (double)(scales[si] / 2)) - pow(b, (double)scales[si]);
                if (v < 0) v = 0;
                ker[j] = sqrt(v);
            }
            for (int o = 0; o < Nc; ++o) {
                double acc = 0;
                for (int j = 0; j < Nc; ++j) acc += ker[j] * cos(M_PI * o * (j + 0.5) / Nc);
                C[o][si] = (float)(2.0 / Nc * acc);
            }
        }
    }

    // workspace carve. Plans (CAD1 fp32 pool, CAD2 fp16 pool):
    //   A: CAD1=8, CAD2=8  -> ~308 MB
    //   B: CAD1=4, CAD2=8  -> ~257 MB
    //   C: CAD1=4, CAD2=4  -> ~231 MB
    int*   degi; float* dh; int* off; int* cursor; int* bsum; int* boff;
    ll*    csrp; float* pool; _Float16* pool16; _Float16* h16;
    float* hacc; float* acc2;
    const int plans[3][2] = {{8, 8}, {4, 8}, {4, 4}};
    int CAD1 = 8, CAD2 = 8;
    for (int attempt = 0; attempt < 3; ++attempt) {
        CAD1 = plans[attempt][0];
        CAD2 = plans[attempt][1];
        char* p = (char*)d_ws;
        auto alloc = [&](size_t bytes) -> void* {
            void* r = (void*)p;
            p += (bytes + 255) & ~(size_t)255;
            return r;
        };
        degi   = (int*)alloc((size_t)NN * 4);
        dh     = (float*)alloc((size_t)NN * 4);
        off    = (int*)alloc((size_t)NN * 4);
        cursor = (int*)alloc((size_t)NN * 4);
        bsum   = (int*)alloc((size_t)NB_SCAN * 4);
        boff   = (int*)alloc((size_t)NB_SCAN * 4);
        csrp   = (ll*)alloc((size_t)NE * 8);
        pool   = (float*)alloc((size_t)CAD1 * CHAIN_ELEMS * 4);
        pool16 = (_Float16*)alloc((size_t)CAD2 * CHAIN_ELEMS * 2);
        h16    = (_Float16*)alloc((size_t)3 * CHAIN_ELEMS * 2);
        hacc   = (float*)alloc((size_t)4 * CHAIN_ELEMS * 4);
        acc2   = (float*)alloc((size_t)6 * CHAIN_ELEMS * 4);
        if ((size_t)(p - (char*)d_ws) <= ws_size) break;
    }

    hipMemsetAsync(degi, 0, (size_t)NN * 4, stream);
    hipMemsetAsync(cursor, 0, (size_t)NN * 4, stream);

    k_deg  <<<(NE + 255) / 256, 256, 0, stream>>>(col, degi);
    k_dh   <<<(NN + 255) / 256, 256, 0, stream>>>(degi, dh);
    k_bsum <<<NB_SCAN, 256, 0, stream>>>(degi, bsum);
    k_bscan<<<1, 256, 0, stream>>>(bsum, boff);
    k_scan2<<<NB_SCAN, 256, 0, stream>>>(degi, boff, off);
    k_fill <<<(NE + 255) / 256, 256, 0, stream>>>(row, col, dh, off, cursor, csrp);

    const int GRID_C = (int)(CH4 / 256);   // 3125

    auto slot = [&](int k) { return pool + (size_t)((k - 1) & (CAD1 - 1)) * CHAIN_ELEMS; };
    auto slot16 = [&](int k) { return pool16 + (size_t)((k - 1) & (CAD2 - 1)) * CHAIN_ELEMS; };

    auto launch_combine = [&](int nt, const float* src, float* accb,
                              CombCfg& cfg, int first, int doabs) {
        const float4* s4 = (const float4*)src;
        const float4* p4 = (const float4*)pool;
        float4* a4 = (float4*)accb;
        if (CAD1 == 8) {
            if (nt == 4) k_combine<8, 4><<<GRID_C, 256, 0, stream>>>(s4, p4, a4, cfg, first, doabs);
        } else {
            if (nt == 4) k_combine<4, 4><<<GRID_C, 256, 0, stream>>>(s4, p4, a4, cfg, first, doabs);
        }
    };

    auto launch_combine16 = [&](int nt, const float* src, float* accb,
                                CombCfg& cfg, int first, int doabs) {
        const float4* s4 = (const float4*)src;
        const h4_t* p4 = (const h4_t*)pool16;
        float4* a4 = (float4*)accb;
        if (CAD2 == 8) {
            if (nt == 3) k_combine16<8, 3><<<GRID_C, 256, 0, stream>>>(s4, p4, a4, cfg, first, doabs);
            if (nt == 2) k_combine16<8, 2><<<GRID_C, 256, 0, stream>>>(s4, p4, a4, cfg, first, doabs);
            if (nt == 1) k_combine16<8, 1><<<GRID_C, 256, 0, stream>>>(s4, p4, a4, cfg, first, doabs);
        } else {
            if (nt == 3) k_combine16<4, 3><<<GRID_C, 256, 0, stream>>>(s4, p4, a4, cfg, first, doabs);
            if (nt == 2) k_combine16<4, 2><<<GRID_C, 256, 0, stream>>>(s4, p4, a4, cfg, first, doabs);
            if (nt == 1) k_combine16<4, 1><<<GRID_C, 256, 0, stream>>>(s4, p4, a4, cfg, first, doabs);
        }
    };

    // ---- phase 1: x -> hacc planes 0..3 (|h| per scale), fp32 chain ----
    {
        const int scl[4] = {0, 1, 2, 3};
        const int pln[4] = {0, 1, 2, 3};
        k_prop<true><<<GRID_PROP, 256, 0, stream>>>(x, nullptr, slot(1),
                                                    off, degi, csrp);
        for (int k = 2; k <= 16; ++k) {
            const float* Tprev = (k == 2) ? x : slot(k - 2);
            k_prop<false><<<GRID_PROP, 256, 0, stream>>>(slot(k - 1), Tprev,
                                                         slot(k), off, degi, csrp);
            if ((k % CAD1) == 0) {
                CombCfg cfg;
                for (int t = 0; t < 4; ++t) {
                    int si = scl[t];
                    cfg.c0[t] = 0.5f * C[0][si];
                    cfg.plane[t] = pln[t];
                    for (int m = 0; m < CAD1; ++m) cfg.ck[t][m] = C[k - CAD1 + 1 + m][si];
                }
                launch_combine(4, x, hacc, cfg, (k == CAD1) ? 1 : 0,
                               (k == 16) ? 1 : 0);
            }
        }
    }

    // ---- phase 2: fp16 chains on hacc planes 0..2 -> acc2 ----
    k_tohalf<<<(int)(3 * CHAIN_ELEMS / 1024), 256, 0, stream>>>(hacc, h16);

    auto run_chain16 = [&](int j, const int* scl, const int* pln, int nt) {
        const _Float16* srch = h16 + (size_t)j * CHAIN_ELEMS;
        const float* src0 = hacc + (size_t)j * CHAIN_ELEMS;
        k_prop16<true><<<GRID_PROP, 256, 0, stream>>>(srch, nullptr, slot16(1),
                                                      off, degi, csrp);
        for (int k = 2; k <= 16; ++k) {
            const _Float16* Tprev = (k == 2) ? srch : slot16(k - 2);
            k_prop16<false><<<GRID_PROP, 256, 0, stream>>>(slot16(k - 1), Tprev,
                                                           slot16(k), off, degi, csrp);
            if ((k % CAD2) == 0) {
                CombCfg cfg;
                for (int t = 0; t < nt; ++t) {
                    int si = scl[t];
                    cfg.c0[t] = 0.5f * C[0][si];
                    cfg.plane[t] = pln[t];
                    for (int m = 0; m < CAD2; ++m) cfg.ck[t][m] = C[k - CAD2 + 1 + m][si];
                }
                launch_combine16(nt, src0, acc2, cfg, (k == CAD2) ? 1 : 0,
                                 (k == 16) ? 1 : 0);
            }
        }
    };

    {
        const int scl0[3] = {1, 2, 3}; const int pln0[3] = {0, 1, 3};
        run_chain16(0, scl0, pln0, 3);
        const int scl1[2] = {2, 3};    const int pln1[2] = {2, 4};
        run_chain16(1, scl1, pln1, 2);
        const int scl2[1] = {3};       const int pln2[1] = {5};
        run_chain16(2, scl2, pln2, 1);
    }

    // ---- moments ----
    dim3 mg(3, NGRAPH);
    k_moments<<<mg, 256, 0, stream>>>(x, hacc, acc2, out);
}

// Round 6
// 1916.779 us; speedup vs baseline: 1.3111x; 1.0363x over previous
//
#include <hip/hip_runtime.h>
#include <math.h>

#define NN 50000
#define NE 800000
#define NGRAPH 100
#define NPG 500
#define NB_SCAN 196
#define NCHUNK 5
#define NPC 100                        // nodes per moments chunk
#define CHAIN_ELEMS ((size_t)NN * 64)
#define CH4 ((size_t)NN * 16)          // float4 (or half4) elements per plane
#define GRID_PROP (NN / 4)             // 4 nodes (waves) per 256-thr block

typedef long long ll;
typedef _Float16 h4_t __attribute__((ext_vector_type(4)));
typedef _Float16 h8_t __attribute__((ext_vector_type(8)));

__device__ __forceinline__ void unpack(ll v, int& r, float& w) {
    r = (int)(v & 0xffffffffLL);
    w = __int_as_float((int)(v >> 32));
}

__device__ __forceinline__ float4 f4fma(float w, float4 v, float4 a) {
    a.x += w * v.x; a.y += w * v.y; a.z += w * v.z; a.w += w * v.w;
    return a;
}

__device__ __forceinline__ float4 h4f4(h4_t h) {
    return make_float4((float)h.x, (float)h.y, (float)h.z, (float)h.w);
}

__device__ __forceinline__ h4_t f4h4(float4 v) {
    h4_t h;
    h.x = (_Float16)v.x; h.y = (_Float16)v.y;
    h.z = (_Float16)v.z; h.w = (_Float16)v.w;
    return h;
}

// ---------------- setup kernels ----------------

__global__ void k_deg(const int* __restrict__ col, int* __restrict__ degi) {
    int e = blockIdx.x * blockDim.x + threadIdx.x;
    if (e < NE) atomicAdd(&degi[col[e]], 1);
}

__global__ void k_dh(const int* __restrict__ degi, float* __restrict__ dh) {
    int i = blockIdx.x * blockDim.x + threadIdx.x;
    if (i < NN) {
        int d = degi[i];
        dh[i] = d > 0 ? (float)(1.0 / sqrt((double)d)) : 0.0f;
    }
}

__global__ void k_bsum(const int* __restrict__ cnt, int* __restrict__ bsum) {
    __shared__ int sh[256];
    int i = blockIdx.x * 256 + threadIdx.x;
    sh[threadIdx.x] = (i < NN) ? cnt[i] : 0;
    __syncthreads();
    for (int s = 128; s > 0; s >>= 1) {
        if (threadIdx.x < s) sh[threadIdx.x] += sh[threadIdx.x + s];
        __syncthreads();
    }
    if (threadIdx.x == 0) bsum[blockIdx.x] = sh[0];
}

__global__ void k_bscan(const int* __restrict__ bsum, int* __restrict__ boff) {
    __shared__ int sh[2][256];
    int v = (threadIdx.x < NB_SCAN) ? bsum[threadIdx.x] : 0;
    int cur = 0;
    sh[0][threadIdx.x] = v;
    __syncthreads();
    for (int s = 1; s < 256; s <<= 1) {
        int val = sh[cur][threadIdx.x];
        if ((int)threadIdx.x >= s) val += sh[cur][threadIdx.x - s];
        sh[cur ^ 1][threadIdx.x] = val;
        cur ^= 1;
        __syncthreads();
    }
    if (threadIdx.x < NB_SCAN) boff[threadIdx.x] = sh[cur][threadIdx.x] - v;
}

__global__ void k_scan2(const int* __restrict__ cnt, const int* __restrict__ boff,
                        int* __restrict__ off) {
    __shared__ int sh[2][256];
    int i = blockIdx.x * 256 + threadIdx.x;
    int v = (i < NN) ? cnt[i] : 0;
    int cur = 0;
    sh[0][threadIdx.x] = v;
    __syncthreads();
    for (int s = 1; s < 256; s <<= 1) {
        int val = sh[cur][threadIdx.x];
        if ((int)threadIdx.x >= s) val += sh[cur][threadIdx.x - s];
        sh[cur ^ 1][threadIdx.x] = val;
        cur ^= 1;
        __syncthreads();
    }
    if (i < NN) off[i] = boff[blockIdx.x] + sh[cur][threadIdx.x] - v;
}

__global__ void k_fill(const int* __restrict__ row, const int* __restrict__ col,
                       const float* __restrict__ dh, const int* __restrict__ off,
                       int* __restrict__ cursor, ll* __restrict__ csrp) {
    int e = blockIdx.x * blockDim.x + threadIdx.x;
    if (e >= NE) return;
    int r = row[e], c = col[e];
    int pos = off[c] + atomicAdd(&cursor[c], 1);
    float w = dh[r] * dh[c];
    csrp[pos] = ((ll)__float_as_int(w) << 32) | (unsigned int)r;
}

// fp32 -> fp16 plane copy (phase-2 gather table init)
__global__ void k_tohalf(const float* __restrict__ src, _Float16* __restrict__ dst) {
    size_t i = ((size_t)blockIdx.x * 256 + threadIdx.x) * 4;
    float4 v = *(const float4*)&src[i];
    *(h4_t*)&dst[i] = f4h4(v);
}

// ---------------- phase-1 recurrence (R0-validated, fp32 [NN][64]) ----------
// wave = 1 node. lane = eg*16 + cq: eg = edge subgroup (0..3), cq = col quad.
// 256 B row gathers, 16 B/lane, 2 accumulators, plain cached loads.

template <bool INIT>
__global__ __launch_bounds__(256) void k_prop(
    const float* __restrict__ Tcur, const float* __restrict__ Tprev,
    float* __restrict__ Tnext, const int* __restrict__ off,
    const int* __restrict__ degi, const ll* __restrict__ csrp) {
    int node = blockIdx.x * 4 + (threadIdx.x >> 6);
    int lane = threadIdx.x & 63;
    int eg = lane >> 4;
    int cq = lane & 15;
    int s = off[node], e = s + degi[node];
    const float* tb = Tcur + (size_t)cq * 4;
    float4 a0 = make_float4(0.f, 0.f, 0.f, 0.f);
    float4 a1 = make_float4(0.f, 0.f, 0.f, 0.f);
    float4 pv = INIT ? make_float4(0.f, 0.f, 0.f, 0.f)
                     : *(const float4*)&Tprev[(size_t)node * 64 + cq * 4];
    int i = s;
    for (; i + 8 <= e; i += 8) {
        int r0, r1; float w0, w1;
        unpack(csrp[i + eg], r0, w0);
        unpack(csrp[i + 4 + eg], r1, w1);
        float4 v0 = *(const float4*)(tb + (size_t)r0 * 64);
        float4 v1 = *(const float4*)(tb + (size_t)r1 * 64);
        a0 = f4fma(w0, v0, a0);
        a1 = f4fma(w1, v1, a1);
    }
    for (; i < e; i += 4) {
        int idx = i + eg;
        bool act = idx < e;
        int r; float w;
        unpack(csrp[act ? idx : (e - 1)], r, w);
        if (!act) w = 0.f;
        float4 v = *(const float4*)(tb + (size_t)r * 64);
        a0 = f4fma(w, v, a0);
    }
    float4 g = make_float4(a0.x + a1.x, a0.y + a1.y, a0.z + a1.z, a0.w + a1.w);
    g.x += __shfl_xor(g.x, 16); g.y += __shfl_xor(g.y, 16);
    g.z += __shfl_xor(g.z, 16); g.w += __shfl_xor(g.w, 16);
    g.x += __shfl_xor(g.x, 32); g.y += __shfl_xor(g.y, 32);
    g.z += __shfl_xor(g.z, 32); g.w += __shfl_xor(g.w, 32);
    float4 t;
    if (INIT) {
        t = make_float4(-g.x, -g.y, -g.z, -g.w);
    } else {
        t = make_float4(-2.f * g.x - pv.x, -2.f * g.y - pv.y,
                        -2.f * g.z - pv.z, -2.f * g.w - pv.w);
    }
    if (eg == 0) *(float4*)&Tnext[(size_t)node * 64 + cq * 4] = t;
}

// ---------------- phase-2 recurrence, fp16 state [NN][64] halves ------------
// h8 geometry: lane = eg*8 + cq; 8 edge slots, 8 lanes/edge, 16 B/lane (h8 =
// full 128 B row in 8 lanes). Halves load-instr count vs R5's h4 (8 B/lane)
// and doubles edge parallelism; lines/edge stays at the minimum 2.
// Weights + accumulation + reduce fp32; only the stored T_k state is fp16.

template <bool INIT>
__global__ __launch_bounds__(256) void k_prop16(
    const _Float16* __restrict__ Tcur, const _Float16* __restrict__ Tprev,
    _Float16* __restrict__ Tnext, const int* __restrict__ off,
    const int* __restrict__ degi, const ll* __restrict__ csrp) {
    int node = blockIdx.x * 4 + (threadIdx.x >> 6);
    int lane = threadIdx.x & 63;
    int eg = lane >> 3;          // 0..7 edge slots
    int cq = lane & 7;           // 0..7, 8 halves (16 B) each
    int s = off[node], e = s + degi[node];
    const _Float16* tb = Tcur + (size_t)cq * 8;
    float accA[8], accB[8];
#pragma unroll
    for (int j = 0; j < 8; ++j) { accA[j] = 0.f; accB[j] = 0.f; }
    int i = s;
    for (; i + 16 <= e; i += 16) {
        int r0, r1; float w0, w1;
        unpack(csrp[i + eg], r0, w0);
        unpack(csrp[i + 8 + eg], r1, w1);
        h8_t h0 = *(const h8_t*)(tb + (size_t)r0 * 64);
        h8_t h1 = *(const h8_t*)(tb + (size_t)r1 * 64);
#pragma unroll
        for (int j = 0; j < 8; ++j) accA[j] += w0 * (float)h0[j];
#pragma unroll
        for (int j = 0; j < 8; ++j) accB[j] += w1 * (float)h1[j];
    }
    for (; i < e; i += 8) {
        int idx = i + eg;
        bool act = idx < e;
        int r; float w;
        unpack(csrp[act ? idx : (e - 1)], r, w);
        if (!act) w = 0.f;
        h8_t h = *(const h8_t*)(tb + (size_t)r * 64);
#pragma unroll
        for (int j = 0; j < 8; ++j) accA[j] += w * (float)h[j];
    }
    float g[8];
#pragma unroll
    for (int j = 0; j < 8; ++j) g[j] = accA[j] + accB[j];
#pragma unroll
    for (int j = 0; j < 8; ++j) {
        g[j] += __shfl_xor(g[j], 8);
        g[j] += __shfl_xor(g[j], 16);
        g[j] += __shfl_xor(g[j], 32);
    }
    if (eg == 0) {               // lanes 0..7 write the 128 B row
        size_t o = (size_t)node * 64 + (size_t)cq * 8;
        h8_t t;
        if (INIT) {
#pragma unroll
            for (int j = 0; j < 8; ++j) t[j] = (_Float16)(-g[j]);
        } else {
            h8_t ph = *(const h8_t*)&Tprev[o];
#pragma unroll
            for (int j = 0; j < 8; ++j)
                t[j] = (_Float16)(-2.f * g[j] - (float)ph[j]);
        }
        *(h8_t*)&Tnext[o] = t;
    }
}

// ---------------- combine: fp32 pool slots (phase 1) ------------------------

struct CombCfg {
    float c0[4];
    float ck[4][8];
    int   plane[4];
};

template <int NS, int NT>
__global__ __launch_bounds__(256) void k_combine(
    const float4* __restrict__ src0, const float4* __restrict__ pool,
    float4* __restrict__ accb, CombCfg cfg, int first, int doabs) {
    size_t v = (size_t)blockIdx.x * 256 + threadIdx.x;   // < NN*16
    float4 tv[NS];
#pragma unroll
    for (int m = 0; m < NS; ++m) tv[m] = pool[(size_t)m * CH4 + v];
    float4 s0 = first ? src0[v] : make_float4(0.f, 0.f, 0.f, 0.f);
#pragma unroll
    for (int t = 0; t < NT; ++t) {
        size_t o = (size_t)cfg.plane[t] * CH4 + v;
        float4 a;
        if (first) {
            float c = cfg.c0[t];
            a = make_float4(c * s0.x, c * s0.y, c * s0.z, c * s0.w);
        } else {
            a = accb[o];
        }
#pragma unroll
        for (int m = 0; m < NS; ++m) a = f4fma(cfg.ck[t][m], tv[m], a);
        if (doabs) a = make_float4(fabsf(a.x), fabsf(a.y), fabsf(a.z), fabsf(a.w));
        accb[o] = a;
    }
}

// ---------------- combine: fp16 pool slots (phase 2), fp32 acc --------------
// src0 (first-call T0 term) stays the exact fp32 hacc plane.

template <int NS, int NT>
__global__ __launch_bounds__(256) void k_combine16(
    const float4* __restrict__ src0, const h4_t* __restrict__ pool,
    float4* __restrict__ accb, CombCfg cfg, int first, int doabs) {
    size_t v = (size_t)blockIdx.x * 256 + threadIdx.x;   // < NN*16
    float4 tv[NS];
#pragma unroll
    for (int m = 0; m < NS; ++m) tv[m] = h4f4(pool[(size_t)m * CH4 + v]);
    float4 s0 = first ? src0[v] : make_float4(0.f, 0.f, 0.f, 0.f);
#pragma unroll
    for (int t = 0; t < NT; ++t) {
        size_t o = (size_t)cfg.plane[t] * CH4 + v;
        float4 a;
        if (first) {
            float c = cfg.c0[t];
            a = make_float4(c * s0.x, c * s0.y, c * s0.z, c * s0.w);
        } else {
            a = accb[o];
        }
#pragma unroll
        for (int m = 0; m < NS; ++m) a = f4fma(cfg.ck[t][m], tv[m], a);
        if (doabs) a = make_float4(fabsf(a.x), fabsf(a.y), fabsf(a.z), fabsf(a.w));
        accb[o] = a;
    }
}

// ---------------- moments: two-pass (chunked partials + finalize) -----------
// Pass 1: grid (3, NGRAPH, NCHUNK), 100 nodes per chunk -> 1500 blocks
// (vs 300 single-pass at 7% occupancy). Partial s1..s4 in fp64.

__global__ void k_mompart(const float* __restrict__ x, const float* __restrict__ hacc,
                          const float* __restrict__ acc2, double* __restrict__ pmom) {
    int g = blockIdx.y;
    int c = blockIdx.z;
    int col = blockIdx.x * 256 + threadIdx.x;
    if (col >= 704) return;
    const float* src;
    int c0;
    if (col < 64)       { src = x;    c0 = col; }
    else if (col < 320) { int p = (col - 64) >> 6;  src = hacc + (size_t)p * CHAIN_ELEMS; c0 = (col - 64) & 63; }
    else                { int p = (col - 320) >> 6; src = acc2 + (size_t)p * CHAIN_ELEMS; c0 = (col - 320) & 63; }
    double s1 = 0, s2 = 0, s3 = 0, s4 = 0;
    int base = g * NPG + c * NPC;
    for (int i = 0; i < NPC; ++i) {
        double v = (double)src[(size_t)(base + i) * 64 + c0];
        double v2 = v * v;
        s1 += v; s2 += v2; s3 += v2 * v; s4 += v2 * v2;
    }
    size_t ob = (((size_t)c * NGRAPH + g) * 704 + col) * 4;
    pmom[ob + 0] = s1;
    pmom[ob + 1] = s2;
    pmom[ob + 2] = s3;
    pmom[ob + 3] = s4;
}

__global__ void k_momfin(const double* __restrict__ pmom, float* __restrict__ out) {
    int g = blockIdx.y;
    int col = blockIdx.x * 256 + threadIdx.x;
    if (col >= 704) return;
    double s1 = 0, s2 = 0, s3 = 0, s4 = 0;
    for (int c = 0; c < NCHUNK; ++c) {
        size_t ob = (((size_t)c * NGRAPH + g) * 704 + col) * 4;
        s1 += pmom[ob + 0];
        s2 += pmom[ob + 1];
        s3 += pmom[ob + 2];
        s4 += pmom[ob + 3];
    }
    double n = (double)NPG;
    double mu = s1 / n;
    double E2 = s2 / n, E3 = s3 / n, E4 = s4 / n;
    double m2 = E2 - mu * mu;
    double m3 = E3 - 3.0 * mu * E2 + 2.0 * mu * mu * mu;
    double m4 = E4 - 4.0 * mu * E3 + 6.0 * mu * mu * E2 - 3.0 * mu * mu * mu * mu;
    float m2f = (float)m2;
    float skew = 0.f, kurt = -3.f;
    if (m2f > 0.f) {
        skew = (float)(m3 / (m2 * sqrt(m2)));
        if (skew > 1e15f) skew = 0.f;
        kurt = (float)(m4 / (m2 * m2) - 3.0);
        if (kurt > 1e15f) kurt = -3.f;
    }
    size_t ob = (size_t)g * 2816 + col;
    out[ob]        = (float)mu;
    out[ob + 704]  = m2f;
    out[ob + 1408] = skew;
    out[ob + 2112] = kurt;
}

// ---------------- host ----------------

extern "C" void kernel_launch(void* const* d_in, const int* in_sizes, int n_in,
                              void* d_out, int out_size, void* d_ws, size_t ws_size,
                              hipStream_t stream) {
    const float* x = (const float*)d_in[0];
    const int* ei  = (const int*)d_in[1];
    const int* row = ei;
    const int* col = ei + NE;
    float* out = (float*)d_out;

    // Chebyshev coefficients [17][4], double precision (matches numpy)
    float C[17][4];
    {
        const int Nc = 17;
        const int scales[4] = {2, 4, 8, 16};
        for (int si = 0; si < 4; ++si) {
            double ker[17];
            for (int j = 0; j < Nc; ++j) {
                double num = cos(M_PI * (j + 0.5) / Nc);
                double b = -num;
                double v = pow(b, (double)(scales[si] / 2)) - pow(b, (double)scales[si]);
                if (v < 0) v = 0;
                ker[j] = sqrt(v);
            }
            for (int o = 0; o < Nc; ++o) {
                double acc = 0;
                for (int j = 0; j < Nc; ++j) acc += ker[j] * cos(M_PI * o * (j + 0.5) / Nc);
                C[o][si] = (float)(2.0 / Nc * acc);
            }
        }
    }

    // workspace carve. Plans (CAD1 fp32 pool, CAD2 fp16 pool):
    //   A: CAD1=8, CAD2=8  -> ~320 MB
    //   B: CAD1=4, CAD2=8  -> ~268 MB
    //   C: CAD1=4, CAD2=4  -> ~242 MB
    int*   degi; float* dh; int* off; int* cursor; int* bsum; int* boff;
    ll*    csrp; float* pool; _Float16* pool16; _Float16* h16;
    float* hacc; float* acc2; double* pmom;
    const int plans[3][2] = {{8, 8}, {4, 8}, {4, 4}};
    int CAD1 = 8, CAD2 = 8;
    for (int attempt = 0; attempt < 3; ++attempt) {
        CAD1 = plans[attempt][0];
        CAD2 = plans[attempt][1];
        char* p = (char*)d_ws;
        auto alloc = [&](size_t bytes) -> void* {
            void* r = (void*)p;
            p += (bytes + 255) & ~(size_t)255;
            return r;
        };
        degi   = (int*)alloc((size_t)NN * 4);
        dh     = (float*)alloc((size_t)NN * 4);
        off    = (int*)alloc((size_t)NN * 4);
        cursor = (int*)alloc((size_t)NN * 4);
        bsum   = (int*)alloc((size_t)NB_SCAN * 4);
        boff   = (int*)alloc((size_t)NB_SCAN * 4);
        csrp   = (ll*)alloc((size_t)NE * 8);
        pool   = (float*)alloc((size_t)CAD1 * CHAIN_ELEMS * 4);
        pool16 = (_Float16*)alloc((size_t)CAD2 * CHAIN_ELEMS * 2);
        h16    = (_Float16*)alloc((size_t)3 * CHAIN_ELEMS * 2);
        hacc   = (float*)alloc((size_t)4 * CHAIN_ELEMS * 4);
        acc2   = (float*)alloc((size_t)6 * CHAIN_ELEMS * 4);
        pmom   = (double*)alloc((size_t)NCHUNK * NGRAPH * 704 * 4 * 8);
        if ((size_t)(p - (char*)d_ws) <= ws_size) break;
    }

    hipMemsetAsync(degi, 0, (size_t)NN * 4, stream);
    hipMemsetAsync(cursor, 0, (size_t)NN * 4, stream);

    k_deg  <<<(NE + 255) / 256, 256, 0, stream>>>(col, degi);
    k_dh   <<<(NN + 255) / 256, 256, 0, stream>>>(degi, dh);
    k_bsum <<<NB_SCAN, 256, 0, stream>>>(degi, bsum);
    k_bscan<<<1, 256, 0, stream>>>(bsum, boff);
    k_scan2<<<NB_SCAN, 256, 0, stream>>>(degi, boff, off);
    k_fill <<<(NE + 255) / 256, 256, 0, stream>>>(row, col, dh, off, cursor, csrp);

    const int GRID_C = (int)(CH4 / 256);   // 3125

    auto slot = [&](int k) { return pool + (size_t)((k - 1) & (CAD1 - 1)) * CHAIN_ELEMS; };
    auto slot16 = [&](int k) { return pool16 + (size_t)((k - 1) & (CAD2 - 1)) * CHAIN_ELEMS; };

    auto launch_combine = [&](int nt, const float* src, float* accb,
                              CombCfg& cfg, int first, int doabs) {
        const float4* s4 = (const float4*)src;
        const float4* p4 = (const float4*)pool;
        float4* a4 = (float4*)accb;
        if (CAD1 == 8) {
            if (nt == 4) k_combine<8, 4><<<GRID_C, 256, 0, stream>>>(s4, p4, a4, cfg, first, doabs);
        } else {
            if (nt == 4) k_combine<4, 4><<<GRID_C, 256, 0, stream>>>(s4, p4, a4, cfg, first, doabs);
        }
    };

    auto launch_combine16 = [&](int nt, const float* src, float* accb,
                                CombCfg& cfg, int first, int doabs) {
        const float4* s4 = (const float4*)src;
        const h4_t* p4 = (const h4_t*)pool16;
        float4* a4 = (float4*)accb;
        if (CAD2 == 8) {
            if (nt == 3) k_combine16<8, 3><<<GRID_C, 256, 0, stream>>>(s4, p4, a4, cfg, first, doabs);
            if (nt == 2) k_combine16<8, 2><<<GRID_C, 256, 0, stream>>>(s4, p4, a4, cfg, first, doabs);
            if (nt == 1) k_combine16<8, 1><<<GRID_C, 256, 0, stream>>>(s4, p4, a4, cfg, first, doabs);
        } else {
            if (nt == 3) k_combine16<4, 3><<<GRID_C, 256, 0, stream>>>(s4, p4, a4, cfg, first, doabs);
            if (nt == 2) k_combine16<4, 2><<<GRID_C, 256, 0, stream>>>(s4, p4, a4, cfg, first, doabs);
            if (nt == 1) k_combine16<4, 1><<<GRID_C, 256, 0, stream>>>(s4, p4, a4, cfg, first, doabs);
        }
    };

    // ---- phase 1: x -> hacc planes 0..3 (|h| per scale), fp32 chain ----
    {
        const int scl[4] = {0, 1, 2, 3};
        const int pln[4] = {0, 1, 2, 3};
        k_prop<true><<<GRID_PROP, 256, 0, stream>>>(x, nullptr, slot(1),
                                                    off, degi, csrp);
        for (int k = 2; k <= 16; ++k) {
            const float* Tprev = (k == 2) ? x : slot(k - 2);
            k_prop<false><<<GRID_PROP, 256, 0, stream>>>(slot(k - 1), Tprev,
                                                         slot(k), off, degi, csrp);
            if ((k % CAD1) == 0) {
                CombCfg cfg;
                for (int t = 0; t < 4; ++t) {
                    int si = scl[t];
                    cfg.c0[t] = 0.5f * C[0][si];
                    cfg.plane[t] = pln[t];
                    for (int m = 0; m < CAD1; ++m) cfg.ck[t][m] = C[k - CAD1 + 1 + m][si];
                }
                launch_combine(4, x, hacc, cfg, (k == CAD1) ? 1 : 0,
                               (k == 16) ? 1 : 0);
            }
        }
    }

    // ---- phase 2: fp16 chains on hacc planes 0..2 -> acc2 ----
    k_tohalf<<<(int)(3 * CHAIN_ELEMS / 1024), 256, 0, stream>>>(hacc, h16);

    auto run_chain16 = [&](int j, const int* scl, const int* pln, int nt) {
        const _Float16* srch = h16 + (size_t)j * CHAIN_ELEMS;
        const float* src0 = hacc + (size_t)j * CHAIN_ELEMS;
        k_prop16<true><<<GRID_PROP, 256, 0, stream>>>(srch, nullptr, slot16(1),
                                                      off, degi, csrp);
        for (int k = 2; k <= 16; ++k) {
            const _Float16* Tprev = (k == 2) ? srch : slot16(k - 2);
            k_prop16<false><<<GRID_PROP, 256, 0, stream>>>(slot16(k - 1), Tprev,
                                                           slot16(k), off, degi, csrp);
            if ((k % CAD2) == 0) {
                CombCfg cfg;
                for (int t = 0; t < nt; ++t) {
                    int si = scl[t];
                    cfg.c0[t] = 0.5f * C[0][si];
                    cfg.plane[t] = pln[t];
                    for (int m = 0; m < CAD2; ++m) cfg.ck[t][m] = C[k - CAD2 + 1 + m][si];
                }
                launch_combine16(nt, src0, acc2, cfg, (k == CAD2) ? 1 : 0,
                                 (k == 16) ? 1 : 0);
            }
        }
    };

    {
        const int scl0[3] = {1, 2, 3}; const int pln0[3] = {0, 1, 3};
        run_chain16(0, scl0, pln0, 3);
        const int scl1[2] = {2, 3};    const int pln1[2] = {2, 4};
        run_chain16(1, scl1, pln1, 2);
        const int scl2[1] = {3};       const int pln2[1] = {5};
        run_chain16(2, scl2, pln2, 1);
    }

    // ---- moments: two-pass ----
    dim3 mg1(3, NGRAPH, NCHUNK);
    k_mompart<<<mg1, 256, 0, stream>>>(x, hacc, acc2, pmom);
    dim3 mg2(3, NGRAPH);
    k_momfin<<<mg2, 256, 0, stream>>>(pmom, out);
}